// Round 15
// baseline (159.440 us; speedup 1.0000x reference)
//
#include <hip/hip_runtime.h>
#include <hip/hip_bf16.h>
#include <hip/hip_fp16.h>

#define N_NODES 20000
#define N_EDGES 640000
#define HID 128
#define HEADS 8
#define HD 16
#define NB_SCAN ((N_NODES + 255) / 256)   // 79
#define CH 192                            // edges per chunk
#define QKV_BLOCKS 625                    // 20000/32
#define NREP 32                           // histogram replicas
#define HIST_BLOCKS 128                   // chunky grid-stride hist blocks

typedef __attribute__((ext_vector_type(8))) short bf16x8;
typedef __attribute__((ext_vector_type(4))) float f32x4;
typedef __attribute__((ext_vector_type(2))) float f32x2;
typedef _Float16 half2_t __attribute__((ext_vector_type(2)));

#if __has_builtin(__builtin_amdgcn_cvt_pk_f32_fp8) && __has_builtin(__builtin_amdgcn_cvt_pk_fp8_f32)
#define FP8_FAST 1
#else
#define FP8_FAST 0
#include <hip/hip_fp8.h>
#endif

__device__ __forceinline__ float bfu(ushort u) {
    union { unsigned i; float f; } x; x.i = ((unsigned)u) << 16; return x.f;
}
__device__ __forceinline__ ushort f2bu(float f) {
    __hip_bfloat16 b = __float2bfloat16(f);
    union { __hip_bfloat16 b; ushort u; } c; c.b = b; return c.u;
}
__device__ __forceinline__ ushort f2hu(float f) {
    __half hh = __float2half(f);
    union { __half h; ushort u; } c; c.h = hh; return c.u;
}
// packed half2 dot-accumulate
__device__ __forceinline__ float fdot2h(unsigned a, unsigned b, float c) {
    union { unsigned u; half2_t h; } A, B;
    A.u = a; B.u = b;
#if __has_builtin(__builtin_amdgcn_fdot2)
    return __builtin_amdgcn_fdot2(A.h, B.h, c, false);
#else
    return c + (float)A.h[0] * (float)B.h[0] + (float)A.h[1] * (float)B.h[1];
#endif
}
// 4x fp8 e4m3 <-> f32
__device__ __forceinline__ unsigned fp8x4_enc(float a, float b, float c, float d) {
#if FP8_FAST
    unsigned w = (unsigned)__builtin_amdgcn_cvt_pk_fp8_f32(a, b, 0, false);
    w = (unsigned)__builtin_amdgcn_cvt_pk_fp8_f32(c, d, (int)w, true);
    return w;
#else
    __hip_fp8_e4m3 e0(a), e1(b), e2(c), e3(d);
    return (unsigned)e0.__x | ((unsigned)e1.__x << 8) |
           ((unsigned)e2.__x << 16) | ((unsigned)e3.__x << 24);
#endif
}
__device__ __forceinline__ void fp8x4_dec(unsigned p, float* o) {
#if FP8_FAST
    f32x2 lo = __builtin_amdgcn_cvt_pk_f32_fp8((int)p, false);
    f32x2 hi = __builtin_amdgcn_cvt_pk_f32_fp8((int)p, true);
    o[0] = lo[0]; o[1] = lo[1]; o[2] = hi[0]; o[3] = hi[1];
#else
#pragma unroll
    for (int i = 0; i < 4; ++i) {
        unsigned char b = (p >> (8 * i)) & 0xff;
        __hip_fp8_e4m3 e; e.__x = b;
        o[i] = (float)e;
    }
#endif
}

// --------------- prep: transpose + bf16-cast all five weight mats -> Wt[0..4]
__global__ __launch_bounds__(256) void prep_kernel(
        const float* __restrict__ Wq, const float* __restrict__ Wk,
        const float* __restrict__ Wv, const float* __restrict__ Wo,
        const float* __restrict__ Wg1, ushort* __restrict__ Wt) {
    const float* srcs[5] = {Wq, Wk, Wv, Wo, Wg1};
    const float* W = srcs[blockIdx.x];
    ushort* out = Wt + (size_t)blockIdx.x * 16384;
    for (int i = threadIdx.x; i < 16384; i += 256) {
        int k = i >> 7, n = i & 127;
        out[n * 128 + k] = f2bu(W[i]);
    }
}

// --------------- fused front: qkv MFMA GEMM (625) | hist+rank (128)
// qkv reads pre-transposed bf16 B-frags straight from L2-hot Wt; LDS = hs only
__global__ __launch_bounds__(256) void front_kernel(
        const float* __restrict__ h, const ushort* __restrict__ Wt,
        const float* __restrict__ bq, const float* __restrict__ bk,
        const float* __restrict__ bv,
        ushort* __restrict__ qb, ushort* __restrict__ kb,
        unsigned char* __restrict__ vb8,
        const int* __restrict__ src,
        int* __restrict__ cnt, int* __restrict__ rank) {
    __shared__ __align__(16) ushort hs[32 * 136];
    const int t = threadIdx.x;
    if (blockIdx.x < QKV_BLOCKS) {
        const int row0 = blockIdx.x * 32;
        // vectorized h staging: float4 -> 4x bf16 packed (8B LDS write)
        for (int i4 = t; i4 < 1024; i4 += 256) {
            const int row = i4 >> 5, c4 = (i4 & 31) * 4;
            const float4 hv = reinterpret_cast<const float4*>(h + (size_t)row0 * 128)[i4];
            ushort* dstp = &hs[row * 136 + c4];
            dstp[0] = f2bu(hv.x); dstp[1] = f2bu(hv.y);
            dstp[2] = f2bu(hv.z); dstp[3] = f2bu(hv.w);
        }
        __syncthreads();
        const int w = t >> 6, lane = t & 63;
        const int rt = w >> 1, half = w & 1;
        const int lrow = lane & 15, lkb = (lane >> 4) * 8;
        bf16x8 a[4];
#pragma unroll
        for (int ks = 0; ks < 4; ++ks)
            a[ks] = *reinterpret_cast<const bf16x8*>(&hs[(rt * 16 + lrow) * 136 + ks * 32 + lkb]);
        __syncthreads();   // hs reused as output staging
        const int rloc0 = rt * 16 + (lane >> 4) * 4;
#define MFMA_COL(MI, col, acc) \
        { \
            _Pragma("unroll") \
            for (int ks = 0; ks < 4; ++ks) { \
                bf16x8 b = *reinterpret_cast<const bf16x8*>( \
                    &Wt[(MI) * 16384 + (col) * 128 + ks * 32 + lkb]); \
                acc = __builtin_amdgcn_mfma_f32_16x16x32_bf16(a[ks], b, acc, 0, 0, 0); \
            } \
        }
#define DO_MAT_F16(MI, BIAS, OUT) \
        { \
        for (int ctp = 0; ctp < 4; ++ctp) { \
            const int col = (ctp * 2 + half) * 16 + lrow; \
            f32x4 acc = {0.f, 0.f, 0.f, 0.f}; \
            MFMA_COL(MI, col, acc) \
            const float bias = BIAS[col]; \
            _Pragma("unroll") \
            for (int r = 0; r < 4; ++r) \
                hs[(rloc0 + r) * 128 + col] = f2hu(acc[r] + bias); \
        } \
        __syncthreads(); \
        { \
            uint4* outp = reinterpret_cast<uint4*>(OUT + (size_t)row0 * 128); \
            const uint4* inp = reinterpret_cast<const uint4*>(hs); \
            outp[t] = inp[t]; \
            outp[t + 256] = inp[t + 256]; \
        } \
        __syncthreads(); \
        }
        DO_MAT_F16(0, bq, qb)
        DO_MAT_F16(1, bk, kb)
        // ---- V (fp8 e4m3 out) ----
        {
        unsigned char* hsb = reinterpret_cast<unsigned char*>(hs);
        for (int ctp = 0; ctp < 4; ++ctp) {
            const int col = (ctp * 2 + half) * 16 + lrow;
            f32x4 acc = {0.f, 0.f, 0.f, 0.f};
            MFMA_COL(2, col, acc)
            const float bias = bv[col];
            const unsigned wpk = fp8x4_enc(acc[0] + bias, acc[1] + bias,
                                           acc[2] + bias, acc[3] + bias);
#pragma unroll
            for (int r = 0; r < 4; ++r)
                hsb[(rloc0 + r) * 128 + col] = (unsigned char)((wpk >> (8 * r)) & 0xff);
        }
        __syncthreads();
        {
            uint4* outp = reinterpret_cast<uint4*>(vb8 + (size_t)row0 * 128);
            const uint4* inp = reinterpret_cast<const uint4*>(hs);
            outp[t] = inp[t];     // 4096 B total
        }
        }
#undef DO_MAT_F16
#undef MFMA_COL
    } else {
        const int b = blockIdx.x - QKV_BLOCKS;
        for (int e = b * 256 + t; e < N_EDGES; e += HIST_BLOCKS * 256) {
            const int rep = (e >> 8) & (NREP - 1);
            rank[e] = atomicAdd(&cnt[rep * N_NODES + src[e]], 1);
        }
    }
}

// scan1 + folded scan2 (last-block-done)
__global__ __launch_bounds__(256) void scan1_kernel(const int* __restrict__ cnt,
        int* __restrict__ repOff, int* __restrict__ startp,
        int* __restrict__ blockSums, int* __restrict__ ticket, int n) {
    __shared__ int sd[256];
    __shared__ int lastFlag;
    const int tid = threadIdx.x;
    const int i = blockIdx.x * 256 + tid;
    int running = 0;
    if (i < n) {
#pragma unroll
        for (int r = 0; r < NREP; ++r) {
            int v = cnt[r * N_NODES + i];
            repOff[r * N_NODES + i] = running;
            running += v;
        }
    }
    sd[tid] = running;
    __syncthreads();
#pragma unroll
    for (int off = 1; off < 256; off <<= 1) {
        int tv = (tid >= off) ? sd[tid - off] : 0;
        __syncthreads();
        sd[tid] += tv;
        __syncthreads();
    }
    if (i < n) startp[i] = sd[tid] - running;
    if (tid == 255) {
        atomicExch(&blockSums[blockIdx.x], sd[255]);
        __threadfence();
        lastFlag = (atomicAdd(ticket, 1) == NB_SCAN - 1);
    }
    __syncthreads();
    if (lastFlag) {
        int v = (tid < NB_SCAN) ? atomicAdd(&blockSums[tid], 0) : 0;
        sd[tid] = v;
        __syncthreads();
#pragma unroll
        for (int off = 1; off < 256; off <<= 1) {
            int tv = (tid >= off) ? sd[tid - off] : 0;
            __syncthreads();
            sd[tid] += tv;
            __syncthreads();
        }
        if (tid < NB_SCAN) blockSums[tid] = sd[tid] - v;   // exclusive
        if (tid == 255) blockSums[NB_SCAN] = sd[255];      // total
    }
}

// --------------- scatter: pos = start + blockSums + repOff + rank (no atomics)
__global__ __launch_bounds__(256) void scatter_kernel(
        const int* __restrict__ src, const int* __restrict__ dst,
        const float* __restrict__ dist, const float* __restrict__ bpp,
        const float* __restrict__ msa, const float* __restrict__ chem,
        const float* __restrict__ rel, const float* __restrict__ chain,
        const float* __restrict__ w_dist, const float* __restrict__ b_dist,
        const float* __restrict__ w_bpp, const float* __restrict__ b_bpp,
        const float* __restrict__ w_msa, const float* __restrict__ b_msa,
        const float* __restrict__ w_chem, const float* __restrict__ b_chem,
        const float* __restrict__ w_rel, const float* __restrict__ b_rel,
        const float* __restrict__ w_chain, const float* __restrict__ b_chain,
        const int* __restrict__ startp, const int* __restrict__ blockSums,
        const int* __restrict__ repOff, const int* __restrict__ rank,
        const float* __restrict__ x,
        uint4* __restrict__ bias16, uint2* __restrict__ meta) {
    const int b = blockIdx.x;
    const int e = b * 256 + threadIdx.x;
    const int s = src[e];
    const int rep = b & (NREP - 1);       // == (e>>8)&31, matches front
    const int pos = startp[s] + blockSums[s >> 8] + repOff[rep * N_NODES + s] + rank[e];
    const int dn = dst[e];
    const float d2 = dist[e] * dist[e];
    const float f_bpp = bpp[e], f_msa = msa[e], f_chem = chem[e];
    const float f_rel = rel[e], f_chain = chain[e];
    ushort o16[8];
#pragma unroll
    for (int hq = 0; hq < 8; ++hq) {
        float bb = -(d2 * w_dist[hq] + b_dist[hq])
                + (f_bpp * w_bpp[hq] + b_bpp[hq])
                + (f_msa * w_msa[hq] + b_msa[hq])
                + (f_chem * w_chem[hq] + b_chem[hq])
                + (f_rel * w_rel[hq] + b_rel[hq])
                + (f_chain * w_chain[hq] + b_chain[hq]);
        o16[hq] = f2bu(bb);
    }
    uint4 b4;
    b4.x = (unsigned)o16[0] | ((unsigned)o16[1] << 16);
    b4.y = (unsigned)o16[2] | ((unsigned)o16[3] << 16);
    b4.z = (unsigned)o16[4] | ((unsigned)o16[5] << 16);
    b4.w = (unsigned)o16[6] | ((unsigned)o16[7] << 16);
    const float* xp = &x[(size_t)dn * 3];
    uint2 mt;
    mt.x = (unsigned)f2bu(xp[0]) | ((unsigned)f2bu(xp[1]) << 16);
    mt.y = (unsigned)f2bu(xp[2]) | ((unsigned)dn << 16);
    bias16[pos] = b4;
    meta[pos]   = mt;
}

// --------------------------------------------- per-node fused softmax + agg
__global__ __launch_bounds__(256) void node_kernel(const ushort* __restrict__ qb,
        const ushort* __restrict__ kb, const unsigned char* __restrict__ vb8,
        const uint4* __restrict__ bias16, const uint2* __restrict__ meta,
        const float* __restrict__ x,
        const int* __restrict__ startp, const int* __restrict__ blockSums,
        ushort* __restrict__ hub, float* __restrict__ disp) {
    __shared__ __align__(16) unsigned qLdsU[4 * 64];   // packed half2, 4 nodes x 128 dims
    __shared__ float xsLds[12];
    __shared__ int   sLds[5];
    __shared__ ushort dnLds[CH];
    __shared__ float xLds[CH * 3];
    __shared__ ushort pbLds[CH * 8];      // exp-weights as bf16
    __shared__ float redN[4][32][9];

    const int t = threadIdx.x;
    const int n0 = blockIdx.x * 4;
    const ushort* biasU = reinterpret_cast<const ushort*>(bias16);

    if (t < 64) {
        const uint4 qv = reinterpret_cast<const uint4*>(qb + (size_t)n0 * 128)[t];
        *reinterpret_cast<uint4*>(&qLdsU[t * 4]) = qv;
    }
    if (t < 12) xsLds[t] = x[(size_t)n0 * 3 + t];
    if (t < 5) {
        int idx = n0 + t;
        sLds[t] = (idx < N_NODES) ? (startp[idx] + blockSums[idx >> 8]) : N_EDGES;
    }
    __syncthreads();

    const int S0 = sLds[0], S4 = sLds[4];
    const int s1r = sLds[1], s2r = sLds[2], s3r = sLds[3];

    const int eg = t >> 5;
    const int dq = t & 31;
    const int hh = dq >> 2;
    const int jj = dq & 3;
    const int j3 = (jj < 3) ? jj : 0;

    float acc0[4] = {0,0,0,0}, acc1[4] = {0,0,0,0};
    float acc2[4] = {0,0,0,0}, acc3[4] = {0,0,0,0};
    float den0 = 0, den1 = 0, den2 = 0, den3 = 0;
    float adx0 = 0, adx1 = 0, adx2 = 0, adx3 = 0;

    for (int base = S0; base < S4; base += CH) {
        const int en = min(CH, S4 - base);
        __syncthreads();
        if (t < en) {
            const uint2 mt = meta[base + t];
            dnLds[t] = (ushort)(mt.y >> 16);
            xLds[t * 3 + 0] = bfu((ushort)(mt.x & 0xffff));
            xLds[t * 3 + 1] = bfu((ushort)(mt.x >> 16));
            xLds[t * 3 + 2] = bfu((ushort)(mt.y & 0xffff));
        }
        __syncthreads();
        // ---- phase A: exp-logits via packed f16 dot2 ----
        const int np = en * 8;
#define PA_BODY(P) { \
            const int e = (P) >> 3, ha = (P) & 7; \
            const int ge = base + e; \
            const int m = (ge >= s1r) + (ge >= s2r) + (ge >= s3r); \
            const ushort* krow = kb + (size_t)dnLds[e] * 128 + ha * 16; \
            const uint4 ka = *reinterpret_cast<const uint4*>(krow); \
            const uint4 kb4 = *reinterpret_cast<const uint4*>(krow + 8); \
            const float bias = bfu(biasU[(size_t)base * 8 + (P)]); \
            const unsigned* qrowU = &qLdsU[m * 64 + ha * 8]; \
            const uint4 qa = *reinterpret_cast<const uint4*>(qrowU); \
            const uint4 qb4 = *reinterpret_cast<const uint4*>(qrowU + 4); \
            float s0 = 0.f, s1 = 0.f, s2 = 0.f, s3 = 0.f; \
            s0 = fdot2h(ka.x, qa.x, s0);   s1 = fdot2h(ka.y, qa.y, s1); \
            s2 = fdot2h(ka.z, qa.z, s2);   s3 = fdot2h(ka.w, qa.w, s3); \
            s0 = fdot2h(kb4.x, qb4.x, s0); s1 = fdot2h(kb4.y, qb4.y, s1); \
            s2 = fdot2h(kb4.z, qb4.z, s2); s3 = fdot2h(kb4.w, qb4.w, s3); \
            pbLds[P] = f2bu(__expf(fmaf((s0 + s1) + (s2 + s3), 0.25f, bias))); \
        }
        {
            int p = t;
            for (; p + 256 < np; p += 512) { PA_BODY(p) PA_BODY(p + 256) }
            if (p < np) PA_BODY(p)
        }
#undef PA_BODY
        __syncthreads();
#define PC_BODY(E, ACC, DEN, ADX, XSV) { \
            const float pe = bfu(pbLds[(E) * 8 + hh]); \
            const unsigned vp = *reinterpret_cast<const unsigned*>( \
                vb8 + (size_t)dnLds[E] * 128 + dq * 4); \
            float vd[4]; \
            fp8x4_dec(vp, vd); \
            ACC[0] = fmaf(pe, vd[0], ACC[0]); \
            ACC[1] = fmaf(pe, vd[1], ACC[1]); \
            ACC[2] = fmaf(pe, vd[2], ACC[2]); \
            ACC[3] = fmaf(pe, vd[3], ACC[3]); \
            DEN += pe; \
            ADX = fmaf(pe, xLds[(E) * 3 + j3] - XSV, ADX); \
        }
#define NODE_C(M, ACC, DEN, ADX) { \
            const int lo = max(sLds[M] - base, 0); \
            const int hi = min(sLds[M + 1] - base, en); \
            const float xsv = xsLds[M * 3 + j3]; \
            int e = lo + eg; \
            for (; e + 8 < hi; e += 16) { \
                PC_BODY(e, ACC, DEN, ADX, xsv) \
                PC_BODY(e + 8, ACC, DEN, ADX, xsv) \
            } \
            if (e < hi) PC_BODY(e, ACC, DEN, ADX, xsv) \
        }
        NODE_C(0, acc0, den0, adx0)
        NODE_C(1, acc1, den1, adx1)
        NODE_C(2, acc2, den2, adx2)
        NODE_C(3, acc3, den3, adx3)
#undef NODE_C
#undef PC_BODY
    }

    const int wv = t >> 6, lane = t & 63;
#define RED_M(M, ACC, DEN, ADX) { \
        float r0 = ACC[0], r1 = ACC[1], r2 = ACC[2], r3 = ACC[3]; \
        float rd = DEN, rx = (jj < 3) ? ADX : 0.f; \
        r0 += __shfl_xor(r0, 32); r1 += __shfl_xor(r1, 32); \
        r2 += __shfl_xor(r2, 32); r3 += __shfl_xor(r3, 32); \
        rd += __shfl_xor(rd, 32); rx += __shfl_xor(rx, 32); \
        if (lane < 32) { \
            redN[wv][lane][0] = r0; redN[wv][lane][1] = r1; \
            redN[wv][lane][2] = r2; redN[wv][lane][3] = r3; \
            redN[wv][lane][4] = rd; redN[wv][lane][5] = rx; \
        } \
        __syncthreads(); \
        if (t < 128) { \
            const int dqr = t >> 2, vi = t & 3; \
            float s = redN[0][dqr][vi] + redN[1][dqr][vi] \
                    + redN[2][dqr][vi] + redN[3][dqr][vi]; \
            float d = redN[0][dqr][4] + redN[1][dqr][4] \
                    + redN[2][dqr][4] + redN[3][dqr][4]; \
            hub[(size_t)(n0 + M) * 128 + t] = f2bu(s / fmaxf(d, 1e-9f)); \
        } \
        if (t < 32) { \
            float v = redN[0][t][5] + redN[1][t][5] + redN[2][t][5] + redN[3][t][5]; \
            float d = redN[0][t][4] + redN[1][t][4] + redN[2][t][4] + redN[3][t][4]; \
            float s = v / fmaxf(d, 1e-9f); \
            s += __shfl_xor(s, 4); s += __shfl_xor(s, 8); s += __shfl_xor(s, 16); \
            if (t < 3) disp[(size_t)(n0 + M) * 3 + t] = s * 0.125f; \
        } \
        __syncthreads(); }
    RED_M(0, acc0, den0, adx0)
    RED_M(1, acc1, den1, adx1)
    RED_M(2, acc2, den2, adx2)
    RED_M(3, acc3, den3, adx3)
#undef RED_M
}

// --------------------- fused output GEMM + gate MLP + coords (MFMA)
__global__ __launch_bounds__(256) void out_kernel(const float* __restrict__ h,
        const float* __restrict__ x, const ushort* __restrict__ hub,
        const ushort* __restrict__ Wt,
        const float* __restrict__ bo, const float* __restrict__ bg1,
        const float* __restrict__ wg2, const float* __restrict__ bg2,
        const float* __restrict__ disp,
        float* __restrict__ hout, float* __restrict__ xout) {
    __shared__ __align__(16) ushort hus[32 * 136];
    __shared__ __align__(16) float hof[32 * 132];
    __shared__ float g1s[32 * 132];
    const int t = threadIdx.x;
    const int row0 = blockIdx.x * 32;
    for (int i8 = t; i8 < 512; i8 += 256) {
        const int row = i8 >> 4, c8 = (i8 & 15) * 8;
        *reinterpret_cast<uint4*>(&hus[row * 136 + c8]) =
            reinterpret_cast<const uint4*>(hub + (size_t)row0 * 128)[i8];
    }
    for (int i4 = t; i4 < 1024; i4 += 256) {
        const int row = i4 >> 5, c4 = (i4 & 31) * 4;
        *reinterpret_cast<float4*>(&hof[row * 132 + c4]) =
            reinterpret_cast<const float4*>(h + (size_t)row0 * 128)[i4];
    }
    __syncthreads();
    const int w = t >> 6, lane = t & 63;
    const int rt = w >> 1, half = w & 1;
    const int lrow = lane & 15, lkb = (lane >> 4) * 8;
    const int rloc = rt * 16 + (lane >> 4) * 4;
    bf16x8 a[4];
#pragma unroll
    for (int ks = 0; ks < 4; ++ks)
        a[ks] = *reinterpret_cast<const bf16x8*>(&hus[(rt * 16 + lrow) * 136 + ks * 32 + lkb]);
    for (int ctp = 0; ctp < 4; ++ctp) {
        const int col = (ctp * 2 + half) * 16 + lrow;
        f32x4 acc = {0.f, 0.f, 0.f, 0.f};
#pragma unroll
        for (int ks = 0; ks < 4; ++ks) {
            bf16x8 b = *reinterpret_cast<const bf16x8*>(&Wt[3 * 16384 + col * 128 + ks * 32 + lkb]);
            acc = __builtin_amdgcn_mfma_f32_16x16x32_bf16(a[ks], b, acc, 0, 0, 0);
        }
        const float bias = bo[col];
#pragma unroll
        for (int r = 0; r < 4; ++r)
            hof[(rloc + r) * 132 + col] += acc[r] + bias;
    }
    __syncthreads();
    for (int i4 = t; i4 < 1024; i4 += 256) {
        const int row = i4 >> 5, c4 = (i4 & 31) * 4;
        *reinterpret_cast<float4*>(hout + (size_t)(row0 + row) * 128 + c4) =
            *reinterpret_cast<const float4*>(&hof[row * 132 + c4]);
    }
    bf16x8 a2[4];
#pragma unroll
    for (int ks = 0; ks < 4; ++ks) {
        const float* fp = &hof[(rt * 16 + lrow) * 132 + ks * 32 + lkb];
        const float4 f0 = *reinterpret_cast<const float4*>(fp);
        const float4 f1 = *reinterpret_cast<const float4*>(fp + 4);
        bf16x8 v;
        v[0] = (short)f2bu(f0.x); v[1] = (short)f2bu(f0.y);
        v[2] = (short)f2bu(f0.z); v[3] = (short)f2bu(f0.w);
        v[4] = (short)f2bu(f1.x); v[5] = (short)f2bu(f1.y);
        v[6] = (short)f2bu(f1.z); v[7] = (short)f2bu(f1.w);
        a2[ks] = v;
    }
    for (int ctp = 0; ctp < 4; ++ctp) {
        const int col = (ctp * 2 + half) * 16 + lrow;
        f32x4 acc = {0.f, 0.f, 0.f, 0.f};
#pragma unroll
        for (int ks = 0; ks < 4; ++ks) {
            bf16x8 b = *reinterpret_cast<const bf16x8*>(&Wt[4 * 16384 + col * 128 + ks * 32 + lkb]);
            acc = __builtin_amdgcn_mfma_f32_16x16x32_bf16(a2[ks], b, acc, 0, 0, 0);
        }
        const float bias = bg1[col];
#pragma unroll
        for (int r = 0; r < 4; ++r) {
            float av = acc[r] + bias;
            g1s[(rloc + r) * 132 + col] = av / (1.f + __expf(-av));
        }
    }
    __syncthreads();
    {
        const int r = t >> 3, j = t & 7;
        float partial = 0.f;
        for (int cc = j; cc < 128; cc += 8) partial += g1s[r * 132 + cc] * wg2[cc];
        partial += __shfl_xor(partial, 1);
        partial += __shfl_xor(partial, 2);
        partial += __shfl_xor(partial, 4);
        const float gate = tanhf(partial + bg2[0]);
        if (j < 3) {
            const int row = row0 + r;
            xout[(size_t)row * 3 + j] = x[(size_t)row * 3 + j] + gate * disp[(size_t)row * 3 + j];
        }
    }
}

// ---------------------------------------------------------------- launcher

extern "C" void kernel_launch(void* const* d_in, const int* in_sizes, int n_in,
                              void* d_out, int out_size, void* d_ws, size_t ws_size,
                              hipStream_t stream) {
    const float* h     = (const float*)d_in[0];
    const float* x     = (const float*)d_in[1];
    const int*   src   = (const int*)d_in[2];
    const int*   dst   = (const int*)d_in[3];
    const float* dist  = (const float*)d_in[4];
    const float* bpp   = (const float*)d_in[5];
    const float* msa   = (const float*)d_in[6];
    const float* chem  = (const float*)d_in[7];
    const float* rel   = (const float*)d_in[8];
    const float* chain = (const float*)d_in[9];
    const float* Wq = (const float*)d_in[10];
    const float* Wk = (const float*)d_in[11];
    const float* Wv = (const float*)d_in[12];
    const float* Wo = (const float*)d_in[13];
    const float* bq = (const float*)d_in[14];
    const float* bk = (const float*)d_in[15];
    const float* bv = (const float*)d_in[16];
    const float* bo = (const float*)d_in[17];
    const float* w_dist = (const float*)d_in[18];  const float* b_dist = (const float*)d_in[19];
    const float* w_bpp  = (const float*)d_in[20];  const float* b_bpp  = (const float*)d_in[21];
    const float* w_msa  = (const float*)d_in[22];  const float* b_msa  = (const float*)d_in[23];
    const float* w_chem = (const float*)d_in[24];  const float* b_chem = (const float*)d_in[25];
    const float* w_rel  = (const float*)d_in[26];  const float* b_rel  = (const float*)d_in[27];
    const float* w_chain= (const float*)d_in[28];  const float* b_chain= (const float*)d_in[29];
    const float* Wg1 = (const float*)d_in[30];
    const float* bg1 = (const float*)d_in[31];
    const float* wg2 = (const float*)d_in[32];
    const float* bg2 = (const float*)d_in[33];

    char* wp = (char*)d_ws;
    const size_t NH2 = (size_t)N_NODES * HID * sizeof(ushort);   // 5,120,000
    ushort* hub   = (ushort*)wp;               wp += NH2;
    ushort* qb    = (ushort*)wp;               wp += NH2;
    ushort* kb    = (ushort*)wp;               wp += NH2;
    unsigned char* vb8 = (unsigned char*)wp;   wp += (size_t)N_NODES * HID;   // fp8
    uint4*  bias16= (uint4*)wp;                wp += (size_t)N_EDGES * 16;
    uint2*  meta  = (uint2*)wp;                wp += (size_t)N_EDGES * 8;
    float*  disp  = (float*)wp;                wp += (size_t)N_NODES * 3 * sizeof(float);
    int* rank     = (int*)wp;                  wp += (size_t)N_EDGES * sizeof(int);
    int* startp   = (int*)wp;                  wp += (size_t)N_NODES * sizeof(int);
    int* cnt      = (int*)wp;                  wp += (size_t)NREP * N_NODES * sizeof(int);
    int* ticket   = (int*)wp;                  wp += sizeof(int);
    int* repOff   = (int*)wp;                  wp += (size_t)NREP * N_NODES * sizeof(int);
    int* blockSums= (int*)wp;                  wp += (size_t)(NB_SCAN + 1) * sizeof(int);
    ushort* Wt    = (ushort*)wp;               wp += (size_t)5 * 16384 * sizeof(ushort);

    float* hout = (float*)d_out;
    float* xout = hout + (size_t)N_NODES * HID;

    // zero cnt + ticket in one memset (contiguous)
    hipMemsetAsync(cnt, 0, ((size_t)NREP * N_NODES + 1) * sizeof(int), stream);
    hipLaunchKernelGGL(prep_kernel, dim3(5), dim3(256), 0, stream,
                       Wq, Wk, Wv, Wo, Wg1, Wt);
    hipLaunchKernelGGL(front_kernel, dim3(QKV_BLOCKS + HIST_BLOCKS), dim3(256), 0, stream,
                       h, Wt, bq, bk, bv, qb, kb, vb8, src, cnt, rank);
    hipLaunchKernelGGL(scan1_kernel, dim3(NB_SCAN), dim3(256), 0, stream,
                       cnt, repOff, startp, blockSums, ticket, N_NODES);
    hipLaunchKernelGGL(scatter_kernel, dim3(N_EDGES / 256), dim3(256), 0, stream,
                       src, dst, dist, bpp, msa, chem, rel, chain,
                       w_dist, b_dist, w_bpp, b_bpp, w_msa, b_msa,
                       w_chem, b_chem, w_rel, b_rel, w_chain, b_chain,
                       startp, blockSums, repOff, rank, x, bias16, meta);
    hipLaunchKernelGGL(node_kernel, dim3(N_NODES / 4), dim3(256), 0, stream,
                       qb, kb, vb8, bias16, meta, x, startp, blockSums, hub, disp);
    hipLaunchKernelGGL(out_kernel, dim3(N_NODES / 32), dim3(256), 0, stream,
                       h, x, hub, Wt, bo, bg1, wg2, bg2, disp, hout, xout);
}

// Round 16
// 145.013 us; speedup vs baseline: 1.0995x; 1.0995x over previous
//
#include <hip/hip_runtime.h>
#include <hip/hip_bf16.h>
#include <hip/hip_fp16.h>

#define N_NODES 20000
#define N_EDGES 640000
#define HID 128
#define HEADS 8
#define HD 16
#define NB_SCAN ((N_NODES + 255) / 256)   // 79
#define CH 192                            // edges per chunk
#define QKV_BLOCKS 625                    // 20000/32
#define NREP 32                           // histogram replicas
#define HIST_BLOCKS 128                   // chunky grid-stride hist blocks

typedef __attribute__((ext_vector_type(8))) short bf16x8;
typedef __attribute__((ext_vector_type(4))) float f32x4;
typedef __attribute__((ext_vector_type(2))) float f32x2;
typedef _Float16 half2_t __attribute__((ext_vector_type(2)));

#if __has_builtin(__builtin_amdgcn_cvt_pk_f32_fp8) && __has_builtin(__builtin_amdgcn_cvt_pk_fp8_f32)
#define FP8_FAST 1
#else
#define FP8_FAST 0
#include <hip/hip_fp8.h>
#endif

__device__ __forceinline__ float bfu(ushort u) {
    union { unsigned i; float f; } x; x.i = ((unsigned)u) << 16; return x.f;
}
__device__ __forceinline__ ushort f2bu(float f) {
    __hip_bfloat16 b = __float2bfloat16(f);
    union { __hip_bfloat16 b; ushort u; } c; c.b = b; return c.u;
}
__device__ __forceinline__ ushort f2hu(float f) {
    __half hh = __float2half(f);
    union { __half h; ushort u; } c; c.h = hh; return c.u;
}
// packed half2 dot-accumulate
__device__ __forceinline__ float fdot2h(unsigned a, unsigned b, float c) {
    union { unsigned u; half2_t h; } A, B;
    A.u = a; B.u = b;
#if __has_builtin(__builtin_amdgcn_fdot2)
    return __builtin_amdgcn_fdot2(A.h, B.h, c, false);
#else
    return c + (float)A.h[0] * (float)B.h[0] + (float)A.h[1] * (float)B.h[1];
#endif
}
// 4x fp8 e4m3 <-> f32
__device__ __forceinline__ unsigned fp8x4_enc(float a, float b, float c, float d) {
#if FP8_FAST
    unsigned w = (unsigned)__builtin_amdgcn_cvt_pk_fp8_f32(a, b, 0, false);
    w = (unsigned)__builtin_amdgcn_cvt_pk_fp8_f32(c, d, (int)w, true);
    return w;
#else
    __hip_fp8_e4m3 e0(a), e1(b), e2(c), e3(d);
    return (unsigned)e0.__x | ((unsigned)e1.__x << 8) |
           ((unsigned)e2.__x << 16) | ((unsigned)e3.__x << 24);
#endif
}
__device__ __forceinline__ void fp8x4_dec(unsigned p, float* o) {
#if FP8_FAST
    f32x2 lo = __builtin_amdgcn_cvt_pk_f32_fp8((int)p, false);
    f32x2 hi = __builtin_amdgcn_cvt_pk_f32_fp8((int)p, true);
    o[0] = lo[0]; o[1] = lo[1]; o[2] = hi[0]; o[3] = hi[1];
#else
#pragma unroll
    for (int i = 0; i < 4; ++i) {
        unsigned char b = (p >> (8 * i)) & 0xff;
        __hip_fp8_e4m3 e; e.__x = b;
        o[i] = (float)e;
    }
#endif
}

// --------------- prep: transpose + bf16-cast 5 weight mats -> Wt[0..4]
// 8 blocks/matrix; LDS-transpose so reads AND writes are coalesced.
__global__ __launch_bounds__(256) void prep_kernel(
        const float* __restrict__ Wq, const float* __restrict__ Wk,
        const float* __restrict__ Wv, const float* __restrict__ Wo,
        const float* __restrict__ Wg1, ushort* __restrict__ Wt) {
    __shared__ ushort tile[128][17];    // [k][n-local], padded
    const float* srcs[5] = {Wq, Wk, Wv, Wo, Wg1};
    const int m = blockIdx.x >> 3;
    const int n0 = (blockIdx.x & 7) * 16;
    const float* W = srcs[m];
    ushort* out = Wt + (size_t)m * 16384;
    const int t = threadIdx.x;
    const int nl = t & 15, kq = t >> 4;           // load: n-local, k-quad base
#pragma unroll
    for (int iter = 0; iter < 8; ++iter) {
        const int k = kq + iter * 16;
        tile[k][nl] = f2bu(W[(size_t)k * 128 + n0 + nl]);
    }
    __syncthreads();
    const int nr = t >> 4, k8 = (t & 15) * 8;     // write: row, k-chunk
    ushort tmp[8];
#pragma unroll
    for (int i = 0; i < 8; ++i) tmp[i] = tile[k8 + i][nr];
    *reinterpret_cast<uint4*>(&out[(size_t)(n0 + nr) * 128 + k8]) =
        *reinterpret_cast<const uint4*>(tmp);
}

// --------------- fused front: qkv MFMA GEMM (625) | hist+rank (128)
// qkv reads pre-transposed bf16 B-frags straight from L2-hot Wt; LDS = hs only
__global__ __launch_bounds__(256) void front_kernel(
        const float* __restrict__ h, const ushort* __restrict__ Wt,
        const float* __restrict__ bq, const float* __restrict__ bk,
        const float* __restrict__ bv,
        ushort* __restrict__ qb, ushort* __restrict__ kb,
        unsigned char* __restrict__ vb8,
        const int* __restrict__ src,
        int* __restrict__ cnt, int* __restrict__ rank) {
    __shared__ __align__(16) ushort hs[32 * 136];
    const int t = threadIdx.x;
    if (blockIdx.x < QKV_BLOCKS) {
        const int row0 = blockIdx.x * 32;
        for (int i4 = t; i4 < 1024; i4 += 256) {
            const int row = i4 >> 5, c4 = (i4 & 31) * 4;
            const float4 hv = reinterpret_cast<const float4*>(h + (size_t)row0 * 128)[i4];
            ushort* dstp = &hs[row * 136 + c4];
            dstp[0] = f2bu(hv.x); dstp[1] = f2bu(hv.y);
            dstp[2] = f2bu(hv.z); dstp[3] = f2bu(hv.w);
        }
        __syncthreads();
        const int w = t >> 6, lane = t & 63;
        const int rt = w >> 1, half = w & 1;
        const int lrow = lane & 15, lkb = (lane >> 4) * 8;
        bf16x8 a[4];
#pragma unroll
        for (int ks = 0; ks < 4; ++ks)
            a[ks] = *reinterpret_cast<const bf16x8*>(&hs[(rt * 16 + lrow) * 136 + ks * 32 + lkb]);
        __syncthreads();   // hs reused as output staging
        const int rloc0 = rt * 16 + (lane >> 4) * 4;
#define MFMA_COL(MI, col, acc) \
        { \
            _Pragma("unroll") \
            for (int ks = 0; ks < 4; ++ks) { \
                bf16x8 b = *reinterpret_cast<const bf16x8*>( \
                    &Wt[(MI) * 16384 + (col) * 128 + ks * 32 + lkb]); \
                acc = __builtin_amdgcn_mfma_f32_16x16x32_bf16(a[ks], b, acc, 0, 0, 0); \
            } \
        }
#define DO_MAT_F16(MI, BIAS, OUT) \
        { \
        for (int ctp = 0; ctp < 4; ++ctp) { \
            const int col = (ctp * 2 + half) * 16 + lrow; \
            f32x4 acc = {0.f, 0.f, 0.f, 0.f}; \
            MFMA_COL(MI, col, acc) \
            const float bias = BIAS[col]; \
            _Pragma("unroll") \
            for (int r = 0; r < 4; ++r) \
                hs[(rloc0 + r) * 128 + col] = f2hu(acc[r] + bias); \
        } \
        __syncthreads(); \
        { \
            uint4* outp = reinterpret_cast<uint4*>(OUT + (size_t)row0 * 128); \
            const uint4* inp = reinterpret_cast<const uint4*>(hs); \
            outp[t] = inp[t]; \
            outp[t + 256] = inp[t + 256]; \
        } \
        __syncthreads(); \
        }
        DO_MAT_F16(0, bq, qb)
        DO_MAT_F16(1, bk, kb)
        // ---- V (fp8 e4m3 out) ----
        {
        unsigned char* hsb = reinterpret_cast<unsigned char*>(hs);
        for (int ctp = 0; ctp < 4; ++ctp) {
            const int col = (ctp * 2 + half) * 16 + lrow;
            f32x4 acc = {0.f, 0.f, 0.f, 0.f};
            MFMA_COL(2, col, acc)
            const float bias = bv[col];
            const unsigned wpk = fp8x4_enc(acc[0] + bias, acc[1] + bias,
                                           acc[2] + bias, acc[3] + bias);
#pragma unroll
            for (int r = 0; r < 4; ++r)
                hsb[(rloc0 + r) * 128 + col] = (unsigned char)((wpk >> (8 * r)) & 0xff);
        }
        __syncthreads();
        {
            uint4* outp = reinterpret_cast<uint4*>(vb8 + (size_t)row0 * 128);
            const uint4* inp = reinterpret_cast<const uint4*>(hs);
            outp[t] = inp[t];     // 4096 B total
        }
        }
#undef DO_MAT_F16
#undef MFMA_COL
    } else {
        const int b = blockIdx.x - QKV_BLOCKS;
        for (int e = b * 256 + t; e < N_EDGES; e += HIST_BLOCKS * 256) {
            const int rep = (e >> 8) & (NREP - 1);
            rank[e] = atomicAdd(&cnt[rep * N_NODES + src[e]], 1);
        }
    }
}

// scan1 + folded scan2 (last-block-done)
__global__ __launch_bounds__(256) void scan1_kernel(const int* __restrict__ cnt,
        int* __restrict__ repOff, int* __restrict__ startp,
        int* __restrict__ blockSums, int* __restrict__ ticket, int n) {
    __shared__ int sd[256];
    __shared__ int lastFlag;
    const int tid = threadIdx.x;
    const int i = blockIdx.x * 256 + tid;
    int running = 0;
    if (i < n) {
#pragma unroll
        for (int r = 0; r < NREP; ++r) {
            int v = cnt[r * N_NODES + i];
            repOff[r * N_NODES + i] = running;
            running += v;
        }
    }
    sd[tid] = running;
    __syncthreads();
#pragma unroll
    for (int off = 1; off < 256; off <<= 1) {
        int tv = (tid >= off) ? sd[tid - off] : 0;
        __syncthreads();
        sd[tid] += tv;
        __syncthreads();
    }
    if (i < n) startp[i] = sd[tid] - running;
    if (tid == 255) {
        atomicExch(&blockSums[blockIdx.x], sd[255]);
        __threadfence();
        lastFlag = (atomicAdd(ticket, 1) == NB_SCAN - 1);
    }
    __syncthreads();
    if (lastFlag) {
        int v = (tid < NB_SCAN) ? atomicAdd(&blockSums[tid], 0) : 0;
        sd[tid] = v;
        __syncthreads();
#pragma unroll
        for (int off = 1; off < 256; off <<= 1) {
            int tv = (tid >= off) ? sd[tid - off] : 0;
            __syncthreads();
            sd[tid] += tv;
            __syncthreads();
        }
        if (tid < NB_SCAN) blockSums[tid] = sd[tid] - v;   // exclusive
        if (tid == 255) blockSums[NB_SCAN] = sd[255];      // total
    }
}

// --------------- scatter: pos = start + blockSums + repOff + rank (no atomics)
__global__ __launch_bounds__(256) void scatter_kernel(
        const int* __restrict__ src, const int* __restrict__ dst,
        const float* __restrict__ dist, const float* __restrict__ bpp,
        const float* __restrict__ msa, const float* __restrict__ chem,
        const float* __restrict__ rel, const float* __restrict__ chain,
        const float* __restrict__ w_dist, const float* __restrict__ b_dist,
        const float* __restrict__ w_bpp, const float* __restrict__ b_bpp,
        const float* __restrict__ w_msa, const float* __restrict__ b_msa,
        const float* __restrict__ w_chem, const float* __restrict__ b_chem,
        const float* __restrict__ w_rel, const float* __restrict__ b_rel,
        const float* __restrict__ w_chain, const float* __restrict__ b_chain,
        const int* __restrict__ startp, const int* __restrict__ blockSums,
        const int* __restrict__ repOff, const int* __restrict__ rank,
        const float* __restrict__ x,
        uint4* __restrict__ bias16, uint2* __restrict__ meta) {
    const int b = blockIdx.x;
    const int e = b * 256 + threadIdx.x;
    const int s = src[e];
    const int rep = b & (NREP - 1);       // == (e>>8)&31, matches front
    const int pos = startp[s] + blockSums[s >> 8] + repOff[rep * N_NODES + s] + rank[e];
    const int dn = dst[e];
    const float d2 = dist[e] * dist[e];
    const float f_bpp = bpp[e], f_msa = msa[e], f_chem = chem[e];
    const float f_rel = rel[e], f_chain = chain[e];
    ushort o16[8];
#pragma unroll
    for (int hq = 0; hq < 8; ++hq) {
        float bb = -(d2 * w_dist[hq] + b_dist[hq])
                + (f_bpp * w_bpp[hq] + b_bpp[hq])
                + (f_msa * w_msa[hq] + b_msa[hq])
                + (f_chem * w_chem[hq] + b_chem[hq])
                + (f_rel * w_rel[hq] + b_rel[hq])
                + (f_chain * w_chain[hq] + b_chain[hq]);
        o16[hq] = f2bu(bb);
    }
    uint4 b4;
    b4.x = (unsigned)o16[0] | ((unsigned)o16[1] << 16);
    b4.y = (unsigned)o16[2] | ((unsigned)o16[3] << 16);
    b4.z = (unsigned)o16[4] | ((unsigned)o16[5] << 16);
    b4.w = (unsigned)o16[6] | ((unsigned)o16[7] << 16);
    const float* xp = &x[(size_t)dn * 3];
    uint2 mt;
    mt.x = (unsigned)f2bu(xp[0]) | ((unsigned)f2bu(xp[1]) << 16);
    mt.y = (unsigned)f2bu(xp[2]) | ((unsigned)dn << 16);
    bias16[pos] = b4;
    meta[pos]   = mt;
}

// --------------------------------------------- per-node fused softmax + agg
__global__ __launch_bounds__(256) void node_kernel(const ushort* __restrict__ qb,
        const ushort* __restrict__ kb, const unsigned char* __restrict__ vb8,
        const uint4* __restrict__ bias16, const uint2* __restrict__ meta,
        const float* __restrict__ x,
        const int* __restrict__ startp, const int* __restrict__ blockSums,
        ushort* __restrict__ hub, float* __restrict__ disp) {
    __shared__ __align__(16) unsigned qLdsU[4 * 64];   // packed half2, 4 nodes x 128 dims
    __shared__ float xsLds[12];
    __shared__ int   sLds[5];
    __shared__ ushort dnLds[CH];
    __shared__ float xLds[CH * 3];
    __shared__ ushort pbLds[CH * 8];      // exp-weights as bf16
    __shared__ float redN[4][32][9];

    const int t = threadIdx.x;
    const int n0 = blockIdx.x * 4;
    const ushort* biasU = reinterpret_cast<const ushort*>(bias16);

    if (t < 64) {
        const uint4 qv = reinterpret_cast<const uint4*>(qb + (size_t)n0 * 128)[t];
        *reinterpret_cast<uint4*>(&qLdsU[t * 4]) = qv;
    }
    if (t < 12) xsLds[t] = x[(size_t)n0 * 3 + t];
    if (t < 5) {
        int idx = n0 + t;
        sLds[t] = (idx < N_NODES) ? (startp[idx] + blockSums[idx >> 8]) : N_EDGES;
    }
    __syncthreads();

    const int S0 = sLds[0], S4 = sLds[4];
    const int s1r = sLds[1], s2r = sLds[2], s3r = sLds[3];

    const int eg = t >> 5;
    const int dq = t & 31;
    const int hh = dq >> 2;
    const int jj = dq & 3;
    const int j3 = (jj < 3) ? jj : 0;

    float acc0[4] = {0,0,0,0}, acc1[4] = {0,0,0,0};
    float acc2[4] = {0,0,0,0}, acc3[4] = {0,0,0,0};
    float den0 = 0, den1 = 0, den2 = 0, den3 = 0;
    float adx0 = 0, adx1 = 0, adx2 = 0, adx3 = 0;

    for (int base = S0; base < S4; base += CH) {
        const int en = min(CH, S4 - base);
        __syncthreads();
        if (t < en) {
            const uint2 mt = meta[base + t];
            dnLds[t] = (ushort)(mt.y >> 16);
            xLds[t * 3 + 0] = bfu((ushort)(mt.x & 0xffff));
            xLds[t * 3 + 1] = bfu((ushort)(mt.x >> 16));
            xLds[t * 3 + 2] = bfu((ushort)(mt.y & 0xffff));
        }
        __syncthreads();
        // ---- phase A: exp-logits via packed f16 dot2 ----
        const int np = en * 8;
#define PA_BODY(P) { \
            const int e = (P) >> 3, ha = (P) & 7; \
            const int ge = base + e; \
            const int m = (ge >= s1r) + (ge >= s2r) + (ge >= s3r); \
            const ushort* krow = kb + (size_t)dnLds[e] * 128 + ha * 16; \
            const uint4 ka = *reinterpret_cast<const uint4*>(krow); \
            const uint4 kb4 = *reinterpret_cast<const uint4*>(krow + 8); \
            const float bias = bfu(biasU[(size_t)base * 8 + (P)]); \
            const unsigned* qrowU = &qLdsU[m * 64 + ha * 8]; \
            const uint4 qa = *reinterpret_cast<const uint4*>(qrowU); \
            const uint4 qb4 = *reinterpret_cast<const uint4*>(qrowU + 4); \
            float s0 = 0.f, s1 = 0.f, s2 = 0.f, s3 = 0.f; \
            s0 = fdot2h(ka.x, qa.x, s0);   s1 = fdot2h(ka.y, qa.y, s1); \
            s2 = fdot2h(ka.z, qa.z, s2);   s3 = fdot2h(ka.w, qa.w, s3); \
            s0 = fdot2h(kb4.x, qb4.x, s0); s1 = fdot2h(kb4.y, qb4.y, s1); \
            s2 = fdot2h(kb4.z, qb4.z, s2); s3 = fdot2h(kb4.w, qb4.w, s3); \
            pbLds[P] = f2bu(__expf(fmaf((s0 + s1) + (s2 + s3), 0.25f, bias))); \
        }
        {
            int p = t;
            for (; p + 256 < np; p += 512) { PA_BODY(p) PA_BODY(p + 256) }
            if (p < np) PA_BODY(p)
        }
#undef PA_BODY
        __syncthreads();
#define PC_BODY(E, ACC, DEN, ADX, XSV) { \
            const float pe = bfu(pbLds[(E) * 8 + hh]); \
            const unsigned vp = *reinterpret_cast<const unsigned*>( \
                vb8 + (size_t)dnLds[E] * 128 + dq * 4); \
            float vd[4]; \
            fp8x4_dec(vp, vd); \
            ACC[0] = fmaf(pe, vd[0], ACC[0]); \
            ACC[1] = fmaf(pe, vd[1], ACC[1]); \
            ACC[2] = fmaf(pe, vd[2], ACC[2]); \
            ACC[3] = fmaf(pe, vd[3], ACC[3]); \
            DEN += pe; \
            ADX = fmaf(pe, xLds[(E) * 3 + j3] - XSV, ADX); \
        }
#define NODE_C(M, ACC, DEN, ADX) { \
            const int lo = max(sLds[M] - base, 0); \
            const int hi = min(sLds[M + 1] - base, en); \
            const float xsv = xsLds[M * 3 + j3]; \
            int e = lo + eg; \
            for (; e + 8 < hi; e += 16) { \
                PC_BODY(e, ACC, DEN, ADX, xsv) \
                PC_BODY(e + 8, ACC, DEN, ADX, xsv) \
            } \
            if (e < hi) PC_BODY(e, ACC, DEN, ADX, xsv) \
        }
        NODE_C(0, acc0, den0, adx0)
        NODE_C(1, acc1, den1, adx1)
        NODE_C(2, acc2, den2, adx2)
        NODE_C(3, acc3, den3, adx3)
#undef NODE_C
#undef PC_BODY
    }

    const int wv = t >> 6, lane = t & 63;
#define RED_M(M, ACC, DEN, ADX) { \
        float r0 = ACC[0], r1 = ACC[1], r2 = ACC[2], r3 = ACC[3]; \
        float rd = DEN, rx = (jj < 3) ? ADX : 0.f; \
        r0 += __shfl_xor(r0, 32); r1 += __shfl_xor(r1, 32); \
        r2 += __shfl_xor(r2, 32); r3 += __shfl_xor(r3, 32); \
        rd += __shfl_xor(rd, 32); rx += __shfl_xor(rx, 32); \
        if (lane < 32) { \
            redN[wv][lane][0] = r0; redN[wv][lane][1] = r1; \
            redN[wv][lane][2] = r2; redN[wv][lane][3] = r3; \
            redN[wv][lane][4] = rd; redN[wv][lane][5] = rx; \
        } \
        __syncthreads(); \
        if (t < 128) { \
            const int dqr = t >> 2, vi = t & 3; \
            float s = redN[0][dqr][vi] + redN[1][dqr][vi] \
                    + redN[2][dqr][vi] + redN[3][dqr][vi]; \
            float d = redN[0][dqr][4] + redN[1][dqr][4] \
                    + redN[2][dqr][4] + redN[3][dqr][4]; \
            hub[(size_t)(n0 + M) * 128 + t] = f2bu(s / fmaxf(d, 1e-9f)); \
        } \
        if (t < 32) { \
            float v = redN[0][t][5] + redN[1][t][5] + redN[2][t][5] + redN[3][t][5]; \
            float d = redN[0][t][4] + redN[1][t][4] + redN[2][t][4] + redN[3][t][4]; \
            float s = v / fmaxf(d, 1e-9f); \
            s += __shfl_xor(s, 4); s += __shfl_xor(s, 8); s += __shfl_xor(s, 16); \
            if (t < 3) disp[(size_t)(n0 + M) * 3 + t] = s * 0.125f; \
        } \
        __syncthreads(); }
    RED_M(0, acc0, den0, adx0)
    RED_M(1, acc1, den1, adx1)
    RED_M(2, acc2, den2, adx2)
    RED_M(3, acc3, den3, adx3)
#undef RED_M
}

// --------------------- fused output GEMM + gate MLP + coords (MFMA)
__global__ __launch_bounds__(256) void out_kernel(const float* __restrict__ h,
        const float* __restrict__ x, const ushort* __restrict__ hub,
        const ushort* __restrict__ Wt,
        const float* __restrict__ bo, const float* __restrict__ bg1,
        const float* __restrict__ wg2, const float* __restrict__ bg2,
        const float* __restrict__ disp,
        float* __restrict__ hout, float* __restrict__ xout) {
    __shared__ __align__(16) ushort hus[32 * 136];
    __shared__ __align__(16) float hof[32 * 132];
    __shared__ float g1s[32 * 132];
    const int t = threadIdx.x;
    const int row0 = blockIdx.x * 32;
    for (int i8 = t; i8 < 512; i8 += 256) {
        const int row = i8 >> 4, c8 = (i8 & 15) * 8;
        *reinterpret_cast<uint4*>(&hus[row * 136 + c8]) =
            reinterpret_cast<const uint4*>(hub + (size_t)row0 * 128)[i8];
    }
    for (int i4 = t; i4 < 1024; i4 += 256) {
        const int row = i4 >> 5, c4 = (i4 & 31) * 4;
        *reinterpret_cast<float4*>(&hof[row * 132 + c4]) =
            reinterpret_cast<const float4*>(h + (size_t)row0 * 128)[i4];
    }
    __syncthreads();
    const int w = t >> 6, lane = t & 63;
    const int rt = w >> 1, half = w & 1;
    const int lrow = lane & 15, lkb = (lane >> 4) * 8;
    const int rloc = rt * 16 + (lane >> 4) * 4;
    bf16x8 a[4];
#pragma unroll
    for (int ks = 0; ks < 4; ++ks)
        a[ks] = *reinterpret_cast<const bf16x8*>(&hus[(rt * 16 + lrow) * 136 + ks * 32 + lkb]);
    for (int ctp = 0; ctp < 4; ++ctp) {
        const int col = (ctp * 2 + half) * 16 + lrow;
        f32x4 acc = {0.f, 0.f, 0.f, 0.f};
#pragma unroll
        for (int ks = 0; ks < 4; ++ks) {
            bf16x8 b = *reinterpret_cast<const bf16x8*>(&Wt[3 * 16384 + col * 128 + ks * 32 + lkb]);
            acc = __builtin_amdgcn_mfma_f32_16x16x32_bf16(a[ks], b, acc, 0, 0, 0);
        }
        const float bias = bo[col];
#pragma unroll
        for (int r = 0; r < 4; ++r)
            hof[(rloc + r) * 132 + col] += acc[r] + bias;
    }
    __syncthreads();
    for (int i4 = t; i4 < 1024; i4 += 256) {
        const int row = i4 >> 5, c4 = (i4 & 31) * 4;
        *reinterpret_cast<float4*>(hout + (size_t)(row0 + row) * 128 + c4) =
            *reinterpret_cast<const float4*>(&hof[row * 132 + c4]);
    }
    bf16x8 a2[4];
#pragma unroll
    for (int ks = 0; ks < 4; ++ks) {
        const float* fp = &hof[(rt * 16 + lrow) * 132 + ks * 32 + lkb];
        const float4 f0 = *reinterpret_cast<const float4*>(fp);
        const float4 f1 = *reinterpret_cast<const float4*>(fp + 4);
        bf16x8 v;
        v[0] = (short)f2bu(f0.x); v[1] = (short)f2bu(f0.y);
        v[2] = (short)f2bu(f0.z); v[3] = (short)f2bu(f0.w);
        v[4] = (short)f2bu(f1.x); v[5] = (short)f2bu(f1.y);
        v[6] = (short)f2bu(f1.z); v[7] = (short)f2bu(f1.w);
        a2[ks] = v;
    }
    for (int ctp = 0; ctp < 4; ++ctp) {
        const int col = (ctp * 2 + half) * 16 + lrow;
        f32x4 acc = {0.f, 0.f, 0.f, 0.f};
#pragma unroll
        for (int ks = 0; ks < 4; ++ks) {
            bf16x8 b = *reinterpret_cast<const bf16x8*>(&Wt[4 * 16384 + col * 128 + ks * 32 + lkb]);
            acc = __builtin_amdgcn_mfma_f32_16x16x32_bf16(a2[ks], b, acc, 0, 0, 0);
        }
        const float bias = bg1[col];
#pragma unroll
        for (int r = 0; r < 4; ++r) {
            float av = acc[r] + bias;
            g1s[(rloc + r) * 132 + col] = av / (1.f + __expf(-av));
        }
    }
    __syncthreads();
    {
        const int r = t >> 3, j = t & 7;
        float partial = 0.f;
        for (int cc = j; cc < 128; cc += 8) partial += g1s[r * 132 + cc] * wg2[cc];
        partial += __shfl_xor(partial, 1);
        partial += __shfl_xor(partial, 2);
        partial += __shfl_xor(partial, 4);
        const float gate = tanhf(partial + bg2[0]);
        if (j < 3) {
            const int row = row0 + r;
            xout[(size_t)row * 3 + j] = x[(size_t)row * 3 + j] + gate * disp[(size_t)row * 3 + j];
        }
    }
}

// ---------------------------------------------------------------- launcher

extern "C" void kernel_launch(void* const* d_in, const int* in_sizes, int n_in,
                              void* d_out, int out_size, void* d_ws, size_t ws_size,
                              hipStream_t stream) {
    const float* h     = (const float*)d_in[0];
    const float* x     = (const float*)d_in[1];
    const int*   src   = (const int*)d_in[2];
    const int*   dst   = (const int*)d_in[3];
    const float* dist  = (const float*)d_in[4];
    const float* bpp   = (const float*)d_in[5];
    const float* msa   = (const float*)d_in[6];
    const float* chem  = (const float*)d_in[7];
    const float* rel   = (const float*)d_in[8];
    const float* chain = (const float*)d_in[9];
    const float* Wq = (const float*)d_in[10];
    const float* Wk = (const float*)d_in[11];
    const float* Wv = (const float*)d_in[12];
    const float* Wo = (const float*)d_in[13];
    const float* bq = (const float*)d_in[14];
    const float* bk = (const float*)d_in[15];
    const float* bv = (const float*)d_in[16];
    const float* bo = (const float*)d_in[17];
    const float* w_dist = (const float*)d_in[18];  const float* b_dist = (const float*)d_in[19];
    const float* w_bpp  = (const float*)d_in[20];  const float* b_bpp  = (const float*)d_in[21];
    const float* w_msa  = (const float*)d_in[22];  const float* b_msa  = (const float*)d_in[23];
    const float* w_chem = (const float*)d_in[24];  const float* b_chem = (const float*)d_in[25];
    const float* w_rel  = (const float*)d_in[26];  const float* b_rel  = (const float*)d_in[27];
    const float* w_chain= (const float*)d_in[28];  const float* b_chain= (const float*)d_in[29];
    const float* Wg1 = (const float*)d_in[30];
    const float* bg1 = (const float*)d_in[31];
    const float* wg2 = (const float*)d_in[32];
    const float* bg2 = (const float*)d_in[33];

    char* wp = (char*)d_ws;
    const size_t NH2 = (size_t)N_NODES * HID * sizeof(ushort);   // 5,120,000
    ushort* hub   = (ushort*)wp;               wp += NH2;
    ushort* qb    = (ushort*)wp;               wp += NH2;
    ushort* kb    = (ushort*)wp;               wp += NH2;
    unsigned char* vb8 = (unsigned char*)wp;   wp += (size_t)N_NODES * HID;   // fp8
    uint4*  bias16= (uint4*)wp;                wp += (size_t)N_EDGES * 16;
    uint2*  meta  = (uint2*)wp;                wp += (size_t)N_EDGES * 8;
    float*  disp  = (float*)wp;                wp += (size_t)N_NODES * 3 * sizeof(float);
    int* rank     = (int*)wp;                  wp += (size_t)N_EDGES * sizeof(int);
    int* startp   = (int*)wp;                  wp += (size_t)N_NODES * sizeof(int);
    int* cnt      = (int*)wp;                  wp += (size_t)NREP * N_NODES * sizeof(int);
    int* ticket   = (int*)wp;                  wp += sizeof(int);
    int* repOff   = (int*)wp;                  wp += (size_t)NREP * N_NODES * sizeof(int);
    int* blockSums= (int*)wp;                  wp += (size_t)(NB_SCAN + 1) * sizeof(int);
    ushort* Wt    = (ushort*)wp;               wp += (size_t)5 * 16384 * sizeof(ushort);

    float* hout = (float*)d_out;
    float* xout = hout + (size_t)N_NODES * HID;

    // zero cnt + ticket in one memset (contiguous)
    hipMemsetAsync(cnt, 0, ((size_t)NREP * N_NODES + 1) * sizeof(int), stream);
    hipLaunchKernelGGL(prep_kernel, dim3(40), dim3(256), 0, stream,
                       Wq, Wk, Wv, Wo, Wg1, Wt);
    hipLaunchKernelGGL(front_kernel, dim3(QKV_BLOCKS + HIST_BLOCKS), dim3(256), 0, stream,
                       h, Wt, bq, bk, bv, qb, kb, vb8, src, cnt, rank);
    hipLaunchKernelGGL(scan1_kernel, dim3(NB_SCAN), dim3(256), 0, stream,
                       cnt, repOff, startp, blockSums, ticket, N_NODES);
    hipLaunchKernelGGL(scatter_kernel, dim3(N_EDGES / 256), dim3(256), 0, stream,
                       src, dst, dist, bpp, msa, chem, rel, chain,
                       w_dist, b_dist, w_bpp, b_bpp, w_msa, b_msa,
                       w_chem, b_chem, w_rel, b_rel, w_chain, b_chain,
                       startp, blockSums, repOff, rank, x, bias16, meta);
    hipLaunchKernelGGL(node_kernel, dim3(N_NODES / 4), dim3(256), 0, stream,
                       qb, kb, vb8, bias16, meta, x, startp, blockSums, hub, disp);
    hipLaunchKernelGGL(out_kernel, dim3(N_NODES / 32), dim3(256), 0, stream,
                       h, x, hub, Wt, bo, bg1, wg2, bg2, disp, hout, xout);
}

// Round 17
// 134.267 us; speedup vs baseline: 1.1875x; 1.0800x over previous
//
#include <hip/hip_runtime.h>
#include <hip/hip_bf16.h>
#include <hip/hip_fp16.h>

#define N_NODES 20000
#define N_EDGES 640000
#define HID 128
#define HEADS 8
#define HD 16
#define NB_SCAN ((N_NODES + 255) / 256)   // 79
#define CH 192                            // edges per chunk
#define QKV_BLOCKS 625                    // 20000/32
#define PREP_BLOCKS 2                     // Wo, Wg1 -> Wt slots 3,4
#define NREP 32                           // histogram replicas
#define HIST_OFF (PREP_BLOCKS + QKV_BLOCKS)   // 627
#define HIST_BLOCKS 128                   // chunky grid-stride hist blocks

typedef __attribute__((ext_vector_type(8))) short bf16x8;
typedef __attribute__((ext_vector_type(4))) float f32x4;
typedef __attribute__((ext_vector_type(2))) float f32x2;
typedef _Float16 half2_t __attribute__((ext_vector_type(2)));

#if __has_builtin(__builtin_amdgcn_cvt_pk_f32_fp8) && __has_builtin(__builtin_amdgcn_cvt_pk_fp8_f32)
#define FP8_FAST 1
#else
#define FP8_FAST 0
#include <hip/hip_fp8.h>
#endif

__device__ __forceinline__ float bfu(ushort u) {
    union { unsigned i; float f; } x; x.i = ((unsigned)u) << 16; return x.f;
}
__device__ __forceinline__ ushort f2bu(float f) {
    __hip_bfloat16 b = __float2bfloat16(f);
    union { __hip_bfloat16 b; ushort u; } c; c.b = b; return c.u;
}
__device__ __forceinline__ ushort f2hu(float f) {
    __half hh = __float2half(f);
    union { __half h; ushort u; } c; c.h = hh; return c.u;
}
// packed half2 dot-accumulate
__device__ __forceinline__ float fdot2h(unsigned a, unsigned b, float c) {
    union { unsigned u; half2_t h; } A, B;
    A.u = a; B.u = b;
#if __has_builtin(__builtin_amdgcn_fdot2)
    return __builtin_amdgcn_fdot2(A.h, B.h, c, false);
#else
    return c + (float)A.h[0] * (float)B.h[0] + (float)A.h[1] * (float)B.h[1];
#endif
}
// 4x fp8 e4m3 <-> f32
__device__ __forceinline__ unsigned fp8x4_enc(float a, float b, float c, float d) {
#if FP8_FAST
    unsigned w = (unsigned)__builtin_amdgcn_cvt_pk_fp8_f32(a, b, 0, false);
    w = (unsigned)__builtin_amdgcn_cvt_pk_fp8_f32(c, d, (int)w, true);
    return w;
#else
    __hip_fp8_e4m3 e0(a), e1(b), e2(c), e3(d);
    return (unsigned)e0.__x | ((unsigned)e1.__x << 8) |
           ((unsigned)e2.__x << 16) | ((unsigned)e3.__x << 24);
#endif
}
__device__ __forceinline__ void fp8x4_dec(unsigned p, float* o) {
#if FP8_FAST
    f32x2 lo = __builtin_amdgcn_cvt_pk_f32_fp8((int)p, false);
    f32x2 hi = __builtin_amdgcn_cvt_pk_f32_fp8((int)p, true);
    o[0] = lo[0]; o[1] = lo[1]; o[2] = hi[0]; o[3] = hi[1];
#else
#pragma unroll
    for (int i = 0; i < 4; ++i) {
        unsigned char b = (p >> (8 * i)) & 0xff;
        __hip_fp8_e4m3 e; e.__x = b;
        o[i] = (float)e;
    }
#endif
}

// --------------- fused front: prep (2) | qkv MFMA GEMM (625) | hist+rank (128)
__global__ __launch_bounds__(256) void front_kernel(
        const float* __restrict__ h,
        const float* __restrict__ bq, const float* __restrict__ bk,
        const float* __restrict__ bv,
        ushort* __restrict__ qb, ushort* __restrict__ kb,
        unsigned char* __restrict__ vb8,
        const int* __restrict__ src,
        int* __restrict__ cnt, int* __restrict__ rank,
        const float* __restrict__ Wq, const float* __restrict__ Wk,
        const float* __restrict__ Wv, const float* __restrict__ Wo,
        const float* __restrict__ Wg1, ushort* __restrict__ Wt) {
    __shared__ __align__(16) ushort hs[32 * 136];
    __shared__ __align__(16) ushort ws[128 * 136];
    const int t = threadIdx.x;
    if (blockIdx.x < PREP_BLOCKS) {
        const float* W = (blockIdx.x == 0) ? Wo : Wg1;
        ushort* out = Wt + (size_t)(3 + blockIdx.x) * 16384;
        for (int i = t; i < 16384; i += 256) {
            int k = i >> 7, n = i & 127;
            out[n * 128 + k] = f2bu(W[i]);
        }
    } else if (blockIdx.x < HIST_OFF) {
        const int row0 = (blockIdx.x - PREP_BLOCKS) * 32;
        for (int i = t; i < 4096; i += 256)
            hs[(i >> 7) * 136 + (i & 127)] = f2bu(h[(size_t)row0 * 128 + i]);
        __syncthreads();
        const int w = t >> 6, lane = t & 63;
        const int rt = w >> 1, half = w & 1;
        const int lrow = lane & 15, lkb = (lane >> 4) * 8;
        bf16x8 a[4];
#pragma unroll
        for (int ks = 0; ks < 4; ++ks)
            a[ks] = *reinterpret_cast<const bf16x8*>(&hs[(rt * 16 + lrow) * 136 + ks * 32 + lkb]);
        __syncthreads();   // hs reused as output staging
        const int rloc0 = rt * 16 + (lane >> 4) * 4;
#define STAGE_W(WSRC) \
        for (int idx = t; idx < 8192; idx += 256) { \
            const int c = idx & 127, kp = idx >> 7; \
            const float w0 = WSRC[(2 * kp) * 128 + c]; \
            const float w1 = WSRC[(2 * kp + 1) * 128 + c]; \
            *reinterpret_cast<unsigned*>(&ws[c * 136 + 2 * kp]) = \
                (unsigned)f2bu(w0) | ((unsigned)f2bu(w1) << 16); \
        } \
        __syncthreads();
#define MFMA_COL(col, acc) \
        { \
            _Pragma("unroll") \
            for (int ks = 0; ks < 4; ++ks) { \
                bf16x8 b = *reinterpret_cast<const bf16x8*>( \
                    &ws[(col) * 136 + ks * 32 + lkb]); \
                acc = __builtin_amdgcn_mfma_f32_16x16x32_bf16(a[ks], b, acc, 0, 0, 0); \
            } \
        }
        // ---- Q and K (f16 out) ----
#define DO_MAT_F16(WSRC, BIAS, OUT) \
        { \
        STAGE_W(WSRC) \
        for (int ctp = 0; ctp < 4; ++ctp) { \
            const int col = (ctp * 2 + half) * 16 + lrow; \
            f32x4 acc = {0.f, 0.f, 0.f, 0.f}; \
            MFMA_COL(col, acc) \
            const float bias = BIAS[col]; \
            _Pragma("unroll") \
            for (int r = 0; r < 4; ++r) \
                hs[(rloc0 + r) * 128 + col] = f2hu(acc[r] + bias); \
        } \
        __syncthreads(); \
        { \
            uint4* outp = reinterpret_cast<uint4*>(OUT + (size_t)row0 * 128); \
            const uint4* inp = reinterpret_cast<const uint4*>(hs); \
            outp[t] = inp[t]; \
            outp[t + 256] = inp[t + 256]; \
        } \
        __syncthreads(); \
        }
        DO_MAT_F16(Wq, bq, qb)
        DO_MAT_F16(Wk, bk, kb)
        // ---- V (fp8 e4m3 out) ----
        {
        STAGE_W(Wv)
        unsigned char* hsb = reinterpret_cast<unsigned char*>(hs);
        for (int ctp = 0; ctp < 4; ++ctp) {
            const int col = (ctp * 2 + half) * 16 + lrow;
            f32x4 acc = {0.f, 0.f, 0.f, 0.f};
            MFMA_COL(col, acc)
            const float bias = bv[col];
            const unsigned wpk = fp8x4_enc(acc[0] + bias, acc[1] + bias,
                                           acc[2] + bias, acc[3] + bias);
#pragma unroll
            for (int r = 0; r < 4; ++r)
                hsb[(rloc0 + r) * 128 + col] = (unsigned char)((wpk >> (8 * r)) & 0xff);
        }
        __syncthreads();
        {
            uint4* outp = reinterpret_cast<uint4*>(vb8 + (size_t)row0 * 128);
            const uint4* inp = reinterpret_cast<const uint4*>(hs);
            outp[t] = inp[t];     // 4096 B total
        }
        }
#undef DO_MAT_F16
#undef MFMA_COL
#undef STAGE_W
    } else {
        const int b = blockIdx.x - HIST_OFF;
        for (int e = b * 256 + t; e < N_EDGES; e += HIST_BLOCKS * 256) {
            const int rep = (e >> 8) & (NREP - 1);
            rank[e] = atomicAdd(&cnt[rep * N_NODES + src[e]], 1);
        }
    }
}

// scan1 + folded scan2 (last-block-done)
__global__ __launch_bounds__(256) void scan1_kernel(const int* __restrict__ cnt,
        int* __restrict__ repOff, int* __restrict__ startp,
        int* __restrict__ blockSums, int* __restrict__ ticket, int n) {
    __shared__ int sd[256];
    __shared__ int lastFlag;
    const int tid = threadIdx.x;
    const int i = blockIdx.x * 256 + tid;
    int running = 0;
    if (i < n) {
#pragma unroll
        for (int r = 0; r < NREP; ++r) {
            int v = cnt[r * N_NODES + i];
            repOff[r * N_NODES + i] = running;
            running += v;
        }
    }
    sd[tid] = running;
    __syncthreads();
#pragma unroll
    for (int off = 1; off < 256; off <<= 1) {
        int tv = (tid >= off) ? sd[tid - off] : 0;
        __syncthreads();
        sd[tid] += tv;
        __syncthreads();
    }
    if (i < n) startp[i] = sd[tid] - running;
    if (tid == 255) {
        atomicExch(&blockSums[blockIdx.x], sd[255]);
        __threadfence();
        lastFlag = (atomicAdd(ticket, 1) == NB_SCAN - 1);
    }
    __syncthreads();
    if (lastFlag) {
        int v = (tid < NB_SCAN) ? atomicAdd(&blockSums[tid], 0) : 0;
        sd[tid] = v;
        __syncthreads();
#pragma unroll
        for (int off = 1; off < 256; off <<= 1) {
            int tv = (tid >= off) ? sd[tid - off] : 0;
            __syncthreads();
            sd[tid] += tv;
            __syncthreads();
        }
        if (tid < NB_SCAN) blockSums[tid] = sd[tid] - v;   // exclusive
        if (tid == 255) blockSums[NB_SCAN] = sd[255];      // total
    }
}

// --------------- scatter: pos = start + blockSums + repOff + rank (no atomics)
__global__ __launch_bounds__(256) void scatter_kernel(
        const int* __restrict__ src, const int* __restrict__ dst,
        const float* __restrict__ dist, const float* __restrict__ bpp,
        const float* __restrict__ msa, const float* __restrict__ chem,
        const float* __restrict__ rel, const float* __restrict__ chain,
        const float* __restrict__ w_dist, const float* __restrict__ b_dist,
        const float* __restrict__ w_bpp, const float* __restrict__ b_bpp,
        const float* __restrict__ w_msa, const float* __restrict__ b_msa,
        const float* __restrict__ w_chem, const float* __restrict__ b_chem,
        const float* __restrict__ w_rel, const float* __restrict__ b_rel,
        const float* __restrict__ w_chain, const float* __restrict__ b_chain,
        const int* __restrict__ startp, const int* __restrict__ blockSums,
        const int* __restrict__ repOff, const int* __restrict__ rank,
        const float* __restrict__ x,
        uint4* __restrict__ bias16, uint2* __restrict__ meta) {
    const int b = blockIdx.x;
    const int e = b * 256 + threadIdx.x;
    const int s = src[e];
    const int rep = b & (NREP - 1);       // == (e>>8)&31, matches front
    const int pos = startp[s] + blockSums[s >> 8] + repOff[rep * N_NODES + s] + rank[e];
    const int dn = dst[e];
    const float d2 = dist[e] * dist[e];
    const float f_bpp = bpp[e], f_msa = msa[e], f_chem = chem[e];
    const float f_rel = rel[e], f_chain = chain[e];
    ushort o16[8];
#pragma unroll
    for (int hq = 0; hq < 8; ++hq) {
        float bb = -(d2 * w_dist[hq] + b_dist[hq])
                + (f_bpp * w_bpp[hq] + b_bpp[hq])
                + (f_msa * w_msa[hq] + b_msa[hq])
                + (f_chem * w_chem[hq] + b_chem[hq])
                + (f_rel * w_rel[hq] + b_rel[hq])
                + (f_chain * w_chain[hq] + b_chain[hq]);
        o16[hq] = f2bu(bb);
    }
    uint4 b4;
    b4.x = (unsigned)o16[0] | ((unsigned)o16[1] << 16);
    b4.y = (unsigned)o16[2] | ((unsigned)o16[3] << 16);
    b4.z = (unsigned)o16[4] | ((unsigned)o16[5] << 16);
    b4.w = (unsigned)o16[6] | ((unsigned)o16[7] << 16);
    const float* xp = &x[(size_t)dn * 3];
    uint2 mt;
    mt.x = (unsigned)f2bu(xp[0]) | ((unsigned)f2bu(xp[1]) << 16);
    mt.y = (unsigned)f2bu(xp[2]) | ((unsigned)dn << 16);
    bias16[pos] = b4;
    meta[pos]   = mt;
}

// --------------------------------------------- per-node fused softmax + agg
__global__ __launch_bounds__(256) void node_kernel(const ushort* __restrict__ qb,
        const ushort* __restrict__ kb, const unsigned char* __restrict__ vb8,
        const uint4* __restrict__ bias16, const uint2* __restrict__ meta,
        const float* __restrict__ x,
        const int* __restrict__ startp, const int* __restrict__ blockSums,
        ushort* __restrict__ hub, float* __restrict__ disp) {
    __shared__ __align__(16) unsigned qLdsU[4 * 64];   // packed half2, 4 nodes x 128 dims
    __shared__ float xsLds[12];
    __shared__ int   sLds[5];
    __shared__ ushort dnLds[CH];
    __shared__ float xLds[CH * 3];
    __shared__ ushort pbLds[CH * 8];      // exp-weights as bf16
    __shared__ float redN[4][32][9];

    const int t = threadIdx.x;
    const int n0 = blockIdx.x * 4;
    const ushort* biasU = reinterpret_cast<const ushort*>(bias16);

    if (t < 64) {
        const uint4 qv = reinterpret_cast<const uint4*>(qb + (size_t)n0 * 128)[t];
        *reinterpret_cast<uint4*>(&qLdsU[t * 4]) = qv;
    }
    if (t < 12) xsLds[t] = x[(size_t)n0 * 3 + t];
    if (t < 5) {
        int idx = n0 + t;
        sLds[t] = (idx < N_NODES) ? (startp[idx] + blockSums[idx >> 8]) : N_EDGES;
    }
    __syncthreads();

    const int S0 = sLds[0], S4 = sLds[4];
    const int s1r = sLds[1], s2r = sLds[2], s3r = sLds[3];

    const int eg = t >> 5;
    const int dq = t & 31;
    const int hh = dq >> 2;
    const int jj = dq & 3;
    const int j3 = (jj < 3) ? jj : 0;

    float acc0[4] = {0,0,0,0}, acc1[4] = {0,0,0,0};
    float acc2[4] = {0,0,0,0}, acc3[4] = {0,0,0,0};
    float den0 = 0, den1 = 0, den2 = 0, den3 = 0;
    float adx0 = 0, adx1 = 0, adx2 = 0, adx3 = 0;

    for (int base = S0; base < S4; base += CH) {
        const int en = min(CH, S4 - base);
        __syncthreads();
        if (t < en) {
            const uint2 mt = meta[base + t];
            dnLds[t] = (ushort)(mt.y >> 16);
            xLds[t * 3 + 0] = bfu((ushort)(mt.x & 0xffff));
            xLds[t * 3 + 1] = bfu((ushort)(mt.x >> 16));
            xLds[t * 3 + 2] = bfu((ushort)(mt.y & 0xffff));
        }
        __syncthreads();
        // ---- phase A: exp-logits via packed f16 dot2 ----
        const int np = en * 8;
#define PA_BODY(P) { \
            const int e = (P) >> 3, ha = (P) & 7; \
            const int ge = base + e; \
            const int m = (ge >= s1r) + (ge >= s2r) + (ge >= s3r); \
            const ushort* krow = kb + (size_t)dnLds[e] * 128 + ha * 16; \
            const uint4 ka = *reinterpret_cast<const uint4*>(krow); \
            const uint4 kb4 = *reinterpret_cast<const uint4*>(krow + 8); \
            const float bias = bfu(biasU[(size_t)base * 8 + (P)]); \
            const unsigned* qrowU = &qLdsU[m * 64 + ha * 8]; \
            const uint4 qa = *reinterpret_cast<const uint4*>(qrowU); \
            const uint4 qb4 = *reinterpret_cast<const uint4*>(qrowU + 4); \
            float s0 = 0.f, s1 = 0.f, s2 = 0.f, s3 = 0.f; \
            s0 = fdot2h(ka.x, qa.x, s0);   s1 = fdot2h(ka.y, qa.y, s1); \
            s2 = fdot2h(ka.z, qa.z, s2);   s3 = fdot2h(ka.w, qa.w, s3); \
            s0 = fdot2h(kb4.x, qb4.x, s0); s1 = fdot2h(kb4.y, qb4.y, s1); \
            s2 = fdot2h(kb4.z, qb4.z, s2); s3 = fdot2h(kb4.w, qb4.w, s3); \
            pbLds[P] = f2bu(__expf(fmaf((s0 + s1) + (s2 + s3), 0.25f, bias))); \
        }
        {
            int p = t;
            for (; p + 256 < np; p += 512) { PA_BODY(p) PA_BODY(p + 256) }
            if (p < np) PA_BODY(p)
        }
#undef PA_BODY
        __syncthreads();
#define PC_BODY(E, ACC, DEN, ADX, XSV) { \
            const float pe = bfu(pbLds[(E) * 8 + hh]); \
            const unsigned vp = *reinterpret_cast<const unsigned*>( \
                vb8 + (size_t)dnLds[E] * 128 + dq * 4); \
            float vd[4]; \
            fp8x4_dec(vp, vd); \
            ACC[0] = fmaf(pe, vd[0], ACC[0]); \
            ACC[1] = fmaf(pe, vd[1], ACC[1]); \
            ACC[2] = fmaf(pe, vd[2], ACC[2]); \
            ACC[3] = fmaf(pe, vd[3], ACC[3]); \
            DEN += pe; \
            ADX = fmaf(pe, xLds[(E) * 3 + j3] - XSV, ADX); \
        }
#define NODE_C(M, ACC, DEN, ADX) { \
            const int lo = max(sLds[M] - base, 0); \
            const int hi = min(sLds[M + 1] - base, en); \
            const float xsv = xsLds[M * 3 + j3]; \
            int e = lo + eg; \
            for (; e + 8 < hi; e += 16) { \
                PC_BODY(e, ACC, DEN, ADX, xsv) \
                PC_BODY(e + 8, ACC, DEN, ADX, xsv) \
            } \
            if (e < hi) PC_BODY(e, ACC, DEN, ADX, xsv) \
        }
        NODE_C(0, acc0, den0, adx0)
        NODE_C(1, acc1, den1, adx1)
        NODE_C(2, acc2, den2, adx2)
        NODE_C(3, acc3, den3, adx3)
#undef NODE_C
#undef PC_BODY
    }

    const int wv = t >> 6, lane = t & 63;
#define RED_M(M, ACC, DEN, ADX) { \
        float r0 = ACC[0], r1 = ACC[1], r2 = ACC[2], r3 = ACC[3]; \
        float rd = DEN, rx = (jj < 3) ? ADX : 0.f; \
        r0 += __shfl_xor(r0, 32); r1 += __shfl_xor(r1, 32); \
        r2 += __shfl_xor(r2, 32); r3 += __shfl_xor(r3, 32); \
        rd += __shfl_xor(rd, 32); rx += __shfl_xor(rx, 32); \
        if (lane < 32) { \
            redN[wv][lane][0] = r0; redN[wv][lane][1] = r1; \
            redN[wv][lane][2] = r2; redN[wv][lane][3] = r3; \
            redN[wv][lane][4] = rd; redN[wv][lane][5] = rx; \
        } \
        __syncthreads(); \
        if (t < 128) { \
            const int dqr = t >> 2, vi = t & 3; \
            float s = redN[0][dqr][vi] + redN[1][dqr][vi] \
                    + redN[2][dqr][vi] + redN[3][dqr][vi]; \
            float d = redN[0][dqr][4] + redN[1][dqr][4] \
                    + redN[2][dqr][4] + redN[3][dqr][4]; \
            hub[(size_t)(n0 + M) * 128 + t] = f2bu(s / fmaxf(d, 1e-9f)); \
        } \
        if (t < 32) { \
            float v = redN[0][t][5] + redN[1][t][5] + redN[2][t][5] + redN[3][t][5]; \
            float d = redN[0][t][4] + redN[1][t][4] + redN[2][t][4] + redN[3][t][4]; \
            float s = v / fmaxf(d, 1e-9f); \
            s += __shfl_xor(s, 4); s += __shfl_xor(s, 8); s += __shfl_xor(s, 16); \
            if (t < 3) disp[(size_t)(n0 + M) * 3 + t] = s * 0.125f; \
        } \
        __syncthreads(); }
    RED_M(0, acc0, den0, adx0)
    RED_M(1, acc1, den1, adx1)
    RED_M(2, acc2, den2, adx2)
    RED_M(3, acc3, den3, adx3)
#undef RED_M
}

// --------------------- fused output GEMM + gate MLP + coords (MFMA)
__global__ __launch_bounds__(256) void out_kernel(const float* __restrict__ h,
        const float* __restrict__ x, const ushort* __restrict__ hub,
        const ushort* __restrict__ Wt,
        const float* __restrict__ bo, const float* __restrict__ bg1,
        const float* __restrict__ wg2, const float* __restrict__ bg2,
        const float* __restrict__ disp,
        float* __restrict__ hout, float* __restrict__ xout) {
    __shared__ __align__(16) ushort hus[32 * 136];
    __shared__ __align__(16) float hof[32 * 132];
    __shared__ float g1s[32 * 132];
    const int t = threadIdx.x;
    const int row0 = blockIdx.x * 32;
    for (int i8 = t; i8 < 512; i8 += 256) {
        const int row = i8 >> 4, c8 = (i8 & 15) * 8;
        *reinterpret_cast<uint4*>(&hus[row * 136 + c8]) =
            reinterpret_cast<const uint4*>(hub + (size_t)row0 * 128)[i8];
    }
    for (int i4 = t; i4 < 1024; i4 += 256) {
        const int row = i4 >> 5, c4 = (i4 & 31) * 4;
        *reinterpret_cast<float4*>(&hof[row * 132 + c4]) =
            reinterpret_cast<const float4*>(h + (size_t)row0 * 128)[i4];
    }
    __syncthreads();
    const int w = t >> 6, lane = t & 63;
    const int rt = w >> 1, half = w & 1;
    const int lrow = lane & 15, lkb = (lane >> 4) * 8;
    const int rloc = rt * 16 + (lane >> 4) * 4;
    bf16x8 a[4];
#pragma unroll
    for (int ks = 0; ks < 4; ++ks)
        a[ks] = *reinterpret_cast<const bf16x8*>(&hus[(rt * 16 + lrow) * 136 + ks * 32 + lkb]);
    for (int ctp = 0; ctp < 4; ++ctp) {
        const int col = (ctp * 2 + half) * 16 + lrow;
        f32x4 acc = {0.f, 0.f, 0.f, 0.f};
#pragma unroll
        for (int ks = 0; ks < 4; ++ks) {
            bf16x8 b = *reinterpret_cast<const bf16x8*>(&Wt[3 * 16384 + col * 128 + ks * 32 + lkb]);
            acc = __builtin_amdgcn_mfma_f32_16x16x32_bf16(a[ks], b, acc, 0, 0, 0);
        }
        const float bias = bo[col];
#pragma unroll
        for (int r = 0; r < 4; ++r)
            hof[(rloc + r) * 132 + col] += acc[r] + bias;
    }
    __syncthreads();
    for (int i4 = t; i4 < 1024; i4 += 256) {
        const int row = i4 >> 5, c4 = (i4 & 31) * 4;
        *reinterpret_cast<float4*>(hout + (size_t)(row0 + row) * 128 + c4) =
            *reinterpret_cast<const float4*>(&hof[row * 132 + c4]);
    }
    bf16x8 a2[4];
#pragma unroll
    for (int ks = 0; ks < 4; ++ks) {
        const float* fp = &hof[(rt * 16 + lrow) * 132 + ks * 32 + lkb];
        const float4 f0 = *reinterpret_cast<const float4*>(fp);
        const float4 f1 = *reinterpret_cast<const float4*>(fp + 4);
        bf16x8 v;
        v[0] = (short)f2bu(f0.x); v[1] = (short)f2bu(f0.y);
        v[2] = (short)f2bu(f0.z); v[3] = (short)f2bu(f0.w);
        v[4] = (short)f2bu(f1.x); v[5] = (short)f2bu(f1.y);
        v[6] = (short)f2bu(f1.z); v[7] = (short)f2bu(f1.w);
        a2[ks] = v;
    }
    for (int ctp = 0; ctp < 4; ++ctp) {
        const int col = (ctp * 2 + half) * 16 + lrow;
        f32x4 acc = {0.f, 0.f, 0.f, 0.f};
#pragma unroll
        for (int ks = 0; ks < 4; ++ks) {
            bf16x8 b = *reinterpret_cast<const bf16x8*>(&Wt[4 * 16384 + col * 128 + ks * 32 + lkb]);
            acc = __builtin_amdgcn_mfma_f32_16x16x32_bf16(a2[ks], b, acc, 0, 0, 0);
        }
        const float bias = bg1[col];
#pragma unroll
        for (int r = 0; r < 4; ++r) {
            float av = acc[r] + bias;
            g1s[(rloc + r) * 132 + col] = av / (1.f + __expf(-av));
        }
    }
    __syncthreads();
    {
        const int r = t >> 3, j = t & 7;
        float partial = 0.f;
        for (int cc = j; cc < 128; cc += 8) partial += g1s[r * 132 + cc] * wg2[cc];
        partial += __shfl_xor(partial, 1);
        partial += __shfl_xor(partial, 2);
        partial += __shfl_xor(partial, 4);
        const float gate = tanhf(partial + bg2[0]);
        if (j < 3) {
            const int row = row0 + r;
            xout[(size_t)row * 3 + j] = x[(size_t)row * 3 + j] + gate * disp[(size_t)row * 3 + j];
        }
    }
}

// ---------------------------------------------------------------- launcher

extern "C" void kernel_launch(void* const* d_in, const int* in_sizes, int n_in,
                              void* d_out, int out_size, void* d_ws, size_t ws_size,
                              hipStream_t stream) {
    const float* h     = (const float*)d_in[0];
    const float* x     = (const float*)d_in[1];
    const int*   src   = (const int*)d_in[2];
    const int*   dst   = (const int*)d_in[3];
    const float* dist  = (const float*)d_in[4];
    const float* bpp   = (const float*)d_in[5];
    const float* msa   = (const float*)d_in[6];
    const float* chem  = (const float*)d_in[7];
    const float* rel   = (const float*)d_in[8];
    const float* chain = (const float*)d_in[9];
    const float* Wq = (const float*)d_in[10];
    const float* Wk = (const float*)d_in[11];
    const float* Wv = (const float*)d_in[12];
    const float* Wo = (const float*)d_in[13];
    const float* bq = (const float*)d_in[14];
    const float* bk = (const float*)d_in[15];
    const float* bv = (const float*)d_in[16];
    const float* bo = (const float*)d_in[17];
    const float* w_dist = (const float*)d_in[18];  const float* b_dist = (const float*)d_in[19];
    const float* w_bpp  = (const float*)d_in[20];  const float* b_bpp  = (const float*)d_in[21];
    const float* w_msa  = (const float*)d_in[22];  const float* b_msa  = (const float*)d_in[23];
    const float* w_chem = (const float*)d_in[24];  const float* b_chem = (const float*)d_in[25];
    const float* w_rel  = (const float*)d_in[26];  const float* b_rel  = (const float*)d_in[27];
    const float* w_chain= (const float*)d_in[28];  const float* b_chain= (const float*)d_in[29];
    const float* Wg1 = (const float*)d_in[30];
    const float* bg1 = (const float*)d_in[31];
    const float* wg2 = (const float*)d_in[32];
    const float* bg2 = (const float*)d_in[33];

    char* wp = (char*)d_ws;
    const size_t NH2 = (size_t)N_NODES * HID * sizeof(ushort);   // 5,120,000
    ushort* hub   = (ushort*)wp;               wp += NH2;
    ushort* qb    = (ushort*)wp;               wp += NH2;
    ushort* kb    = (ushort*)wp;               wp += NH2;
    unsigned char* vb8 = (unsigned char*)wp;   wp += (size_t)N_NODES * HID;   // fp8
    uint4*  bias16= (uint4*)wp;                wp += (size_t)N_EDGES * 16;
    uint2*  meta  = (uint2*)wp;                wp += (size_t)N_EDGES * 8;
    float*  disp  = (float*)wp;                wp += (size_t)N_NODES * 3 * sizeof(float);
    int* rank     = (int*)wp;                  wp += (size_t)N_EDGES * sizeof(int);
    int* startp   = (int*)wp;                  wp += (size_t)N_NODES * sizeof(int);
    int* cnt      = (int*)wp;                  wp += (size_t)NREP * N_NODES * sizeof(int);
    int* ticket   = (int*)wp;                  wp += sizeof(int);
    int* repOff   = (int*)wp;                  wp += (size_t)NREP * N_NODES * sizeof(int);
    int* blockSums= (int*)wp;                  wp += (size_t)(NB_SCAN + 1) * sizeof(int);
    ushort* Wt    = (ushort*)wp;               wp += (size_t)5 * 16384 * sizeof(ushort);

    float* hout = (float*)d_out;
    float* xout = hout + (size_t)N_NODES * HID;

    // zero cnt + ticket in one memset (contiguous)
    hipMemsetAsync(cnt, 0, ((size_t)NREP * N_NODES + 1) * sizeof(int), stream);
    hipLaunchKernelGGL(front_kernel, dim3(HIST_OFF + HIST_BLOCKS), dim3(256), 0, stream,
                       h, bq, bk, bv, qb, kb, vb8,
                       src, cnt, rank, Wq, Wk, Wv, Wo, Wg1, Wt);
    hipLaunchKernelGGL(scan1_kernel, dim3(NB_SCAN), dim3(256), 0, stream,
                       cnt, repOff, startp, blockSums, ticket, N_NODES);
    hipLaunchKernelGGL(scatter_kernel, dim3(N_EDGES / 256), dim3(256), 0, stream,
                       src, dst, dist, bpp, msa, chem, rel, chain,
                       w_dist, b_dist, w_bpp, b_bpp, w_msa, b_msa,
                       w_chem, b_chem, w_rel, b_rel, w_chain, b_chain,
                       startp, blockSums, repOff, rank, x, bias16, meta);
    hipLaunchKernelGGL(node_kernel, dim3(N_NODES / 4), dim3(256), 0, stream,
                       qb, kb, vb8, bias16, meta, x, startp, blockSums, hub, disp);
    hipLaunchKernelGGL(out_kernel, dim3(N_NODES / 32), dim3(256), 0, stream,
                       h, x, hub, Wt, bo, bg1, wg2, bg2, disp, hout, xout);
}